// Round 8
// baseline (327.110 us; speedup 1.0000x reference)
//
#include <hip/hip_runtime.h>
#include <hip/hip_bf16.h>

// ---------------------------------------------------------------------------
// MVoT token processor: out = hidden + MLP_{type}(LN(hidden)), type in {0,1}
// Partition tokens by type -> dense bf16 MFMA GEMMs (half the reference FLOPs).
// GEMM: R7's 4-wave 128x128 geometry + 3-BUFFER 2-DEEP PREFETCH: tile u
// stages tile u+2, end-of-tile wait is counted vmcnt(4) (drains u+1, leaves
// u+2 in flight -> ~1300cyc of load flight time vs R7's ~300). R1==R7 at
// 147us proved conflicts/barriers are off the critical path; the vm wait is.
// ---------------------------------------------------------------------------

#define H_DIM 2048

typedef __attribute__((ext_vector_type(8))) short s16x8;   // 8 bf16 (4 VGPRs)
typedef __attribute__((ext_vector_type(4))) float f32x4;   // MFMA accumulator
typedef __attribute__((ext_vector_type(4))) int   i32x4;   // asm ds_read dst

typedef __attribute__((address_space(1))) const unsigned int gu32;
typedef __attribute__((address_space(3))) unsigned int lu32;
typedef __attribute__((address_space(3))) short lds_s;

__device__ __forceinline__ void load_lds16(const void* g, void* l) {
  // async global->LDS, 16B per lane; LDS dest = wave-uniform base + lane*16
  __builtin_amdgcn_global_load_lds((gu32*)g, (lu32*)l, 16, 0, 0);
}

__device__ __forceinline__ s16x8 asbf(i32x4 v) {
  union { i32x4 i; s16x8 s; } u; u.i = v; return u.s;
}

// ---------------------------------------------------------------------------
// Partition: stable scan of token_type_ids. text (type==0) first, padded to
// 128 rows (BM), then image (type==1), padded. Single block, deterministic.
// ctrl: [0]=Mt [1]=Mt_pad [2]=Mi [3]=Mi_pad [4]=total_rows
// ---------------------------------------------------------------------------
__global__ __launch_bounds__(256) void partition_kernel(
    const int* __restrict__ tt, int T, int* __restrict__ ctrl,
    int* __restrict__ pos, int* __restrict__ rowid) {
  __shared__ int psum[256];
  const int tid = threadIdx.x;
  const int npt = T >> 8;
  const int base = tid * npt;
  int cnt = 0;
  for (int i = 0; i < npt; ++i) cnt += (tt[base + i] == 0);
  psum[tid] = cnt;
  __syncthreads();
  for (int off = 1; off < 256; off <<= 1) {
    int v = psum[tid];
    int add = (tid >= off) ? psum[tid - off] : 0;
    __syncthreads();
    psum[tid] = v + add;
    __syncthreads();
  }
  const int Mt = psum[255];
  const int Mt_pad = (Mt + 127) & ~127;
  int tpos = psum[tid] - cnt;
  int ipos = base - tpos;
  for (int i = 0; i < npt; ++i) {
    const int tok = base + i;
    int p;
    if (tt[tok] == 0) p = tpos++;
    else              p = Mt_pad + ipos++;
    pos[tok] = p;
    rowid[p] = tok;
  }
  const int Mi = T - Mt;
  const int Mi_pad = (Mi + 127) & ~127;
  for (int g = Mt + tid; g < Mt_pad; g += 256) rowid[g] = -1;
  for (int g = Mt_pad + Mi + tid; g < Mt_pad + Mi_pad; g += 256) rowid[g] = -1;
  if (tid == 0) {
    ctrl[0] = Mt; ctrl[1] = Mt_pad; ctrl[2] = Mi; ctrl[3] = Mi_pad;
    ctrl[4] = Mt_pad + Mi_pad;
  }
}

// ---------------------------------------------------------------------------
// Weight transpose + fp32->bf16: W[k][n] -> WT[n][k] (B^T layout for GEMM)
// ---------------------------------------------------------------------------
__global__ __launch_bounds__(256) void transpose_to_bf16(
    const float* __restrict__ W, __hip_bfloat16* __restrict__ WT) {
  __shared__ float tile[32][33];
  const int bx = blockIdx.x, by = blockIdx.y;
  const int tid = threadIdx.x;
  const int r = tid >> 3, c4 = (tid & 7) * 4;
  const float4 v = *(const float4*)(W + (size_t)(by * 32 + r) * H_DIM + bx * 32 + c4);
  tile[r][c4 + 0] = v.x; tile[r][c4 + 1] = v.y;
  tile[r][c4 + 2] = v.z; tile[r][c4 + 3] = v.w;
  __syncthreads();
  union { ushort u[4]; ushort4 v4; } pk;
#pragma unroll
  for (int j = 0; j < 4; ++j) {
    __hip_bfloat16 h = __float2bfloat16(tile[c4 + j][r]);
    pk.u[j] = *(const ushort*)&h;
  }
  *(ushort4*)(WT + (size_t)(bx * 32 + r) * H_DIM + by * 32 + c4) = pk.v4;
}

// ---------------------------------------------------------------------------
// LayerNorm (fp32) -> bf16, scatter row to its gathered position.
// ---------------------------------------------------------------------------
__global__ __launch_bounds__(256) void ln_scatter_kernel(
    const float* __restrict__ X, const float* __restrict__ gamma,
    const float* __restrict__ beta, const int* __restrict__ pos,
    __hip_bfloat16* __restrict__ XG) {
  const int t = blockIdx.x, tid = threadIdx.x;
  const float* row = X + (size_t)t * H_DIM;
  float x[8];
  {
    float4 v0 = *(const float4*)(row + tid * 8);
    float4 v1 = *(const float4*)(row + tid * 8 + 4);
    x[0] = v0.x; x[1] = v0.y; x[2] = v0.z; x[3] = v0.w;
    x[4] = v1.x; x[5] = v1.y; x[6] = v1.z; x[7] = v1.w;
  }
  float s = 0.f, q = 0.f;
#pragma unroll
  for (int j = 0; j < 8; ++j) { s += x[j]; q += x[j] * x[j]; }
#pragma unroll
  for (int off = 32; off > 0; off >>= 1) {
    s += __shfl_down(s, off);
    q += __shfl_down(q, off);
  }
  __shared__ float ls[4], lq[4];
  if ((tid & 63) == 0) { ls[tid >> 6] = s; lq[tid >> 6] = q; }
  __syncthreads();
  const float S = ls[0] + ls[1] + ls[2] + ls[3];
  const float Q = lq[0] + lq[1] + lq[2] + lq[3];
  const float mu = S * (1.0f / H_DIM);
  const float var = Q * (1.0f / H_DIM) - mu * mu;
  const float rstd = rsqrtf(var + 1e-12f);
  const int p = pos[t];
  float4 g0 = *(const float4*)(gamma + tid * 8);
  float4 g1 = *(const float4*)(gamma + tid * 8 + 4);
  float4 b0 = *(const float4*)(beta + tid * 8);
  float4 b1 = *(const float4*)(beta + tid * 8 + 4);
  float g[8] = {g0.x, g0.y, g0.z, g0.w, g1.x, g1.y, g1.z, g1.w};
  float b[8] = {b0.x, b0.y, b0.z, b0.w, b1.x, b1.y, b1.z, b1.w};
  union { ushort u[8]; int4 v; } pk;
#pragma unroll
  for (int j = 0; j < 8; ++j) {
    float y = (x[j] - mu) * rstd * g[j] + b[j];
    __hip_bfloat16 h = __float2bfloat16(y);
    pk.u[j] = *(const ushort*)&h;
  }
  *(int4*)(XG + (size_t)p * H_DIM + tid * 8) = pk.v;
}

// --- asm helpers for the GEMM inner loop -----------------------------------
#define DSRD(dst, addr, OFF) \
  asm volatile("ds_read_b128 %0, %1 offset:" OFF : "=v"(dst) : "v"(addr))
#define PBAR asm volatile("s_barrier" ::: "memory")
#define SB0  __builtin_amdgcn_sched_barrier(0)
#define LGKM0 do { \
  asm volatile("s_waitcnt lgkmcnt(0)" ::: "memory"); SB0; } while (0)

// ---------------------------------------------------------------------------
// 4-wave 128x128 GEMM, BK=32, 3-buffer 2-deep prefetch. 256 thr = 4 waves
// (wm=w>>1, wn=w&1), per-wave 64x64 = acc[4][4] frags of 16x16x32.
// LDS 48 KiB: Alds/Blds [3 buf][64 macro-rows][64 elems]; macro-row mr packs
// rows {2mr,2mr+1} x 32 k as 8 granules of 8 elems, granule g at position
// g^(mr&7) (conflict-free ds_read_b128, element-traced R6/R7; R7 PASSED with
// this exact layout). Staging = pre-swizzled GLOBAL source + linear LDS dest.
//
// Pipeline: tile u reads buf u%3, stages tile u+2 into buf (u+2)%3.
//   TILE(u): STAGE(u+2) -> ds_read(u) -> lgkm0 -> 16 MFMA -> vmcnt(4) -> bar
// vmcnt(4): outstanding at wait = stage(u+2)[4, this tile] + stage(u+1)[4,
// last tile] = 8 -> drains stage(u+1) (a full ~1300cyc old), leaves stage(u+2)
// in flight. NEVER vmcnt(0) in loop (T4).
// Buffer lifetime: buf X read @X (retired via lgkm0 before bar X), overwritten
// @X+1 (after bar X), re-read @X+3 (drained end of X+2 + bar). Tail uses
// clamped redundant staging to keep counts uniform; tile 63 standalone.
// ---------------------------------------------------------------------------
template <int EPI>
__global__ __launch_bounds__(256, 2) void gemmk(
    const __hip_bfloat16* __restrict__ A,
    const __hip_bfloat16* __restrict__ WTt, const __hip_bfloat16* __restrict__ WTi,
    const float* __restrict__ bt, const float* __restrict__ bi,
    const int* __restrict__ ctrl, const int* __restrict__ rowid,
    __hip_bfloat16* __restrict__ Hout,
    const float* __restrict__ resid, float* __restrict__ Out) {
  constexpr int K = H_DIM;
  constexpr int NT = K / 32;            // 64 K-tiles
  const int Mt_pad = ctrl[1];
  const int total = ctrl[4];
  // 1056 blocks = 8 XCD-groups x 132 (66 m-tiles x 2 n-cols): each XCD keeps
  // its 2 B-panels (1 MB) L2-resident (same mapping as R7, known-good).
  const int bid = blockIdx.x;
  const int swz = (bid & 7) * 132 + (bid >> 3);
  const int m0 = (swz % 66) * 128;
  const int n0 = (swz / 66) * 128;
  if (m0 >= total) return;
  const bool is_text = (m0 < Mt_pad);
  const short* Ag = (const short*)A;
  const short* Bg = (const short*)(is_text ? WTt : WTi);
  const float* bias = is_text ? bt : bi;

  __shared__ __align__(16) short Alds[3][4096];   // [buf][64 mr * 64] = 8 KiB/buf
  __shared__ __align__(16) short Blds[3][4096];

  const int tid = threadIdx.x;
  const int w = tid >> 6, l = tid & 63;           // 4 waves
  const int wm = w >> 1, wn = w & 1;

  // ---- staging lane constants (pre-swizzled global source)
  const int srow8 = l >> 3;               // macro-row within this lane-set's 8
  const int sg = (l & 7) ^ srow8;         // granule fetched for position l&7
  const int sRowAdj = sg >> 2;            // row parity within macro-row
  const int sKAdj = (sg & 3) * 8;         // k offset 0..24

  // stage half c2 (32 macro-rows = 4KB) of A/B K-tile kk into buf bI
  auto stageA = [&](int bI, int c2, int kk) {
    const int mr = c2 * 32 + w * 8 + srow8;
    const short* src = Ag + (size_t)(m0 + mr * 2 + sRowAdj) * K + kk + sKAdj;
    load_lds16(src, &Alds[bI][(c2 * 32 + w * 8) * 64]);
  };
  auto stageB = [&](int bI, int c2, int kk) {
    const int mr = c2 * 32 + w * 8 + srow8;
    const short* src = Bg + (size_t)(n0 + mr * 2 + sRowAdj) * K + kk + sKAdj;
    load_lds16(src, &Blds[bI][(c2 * 32 + w * 8) * 64]);
  };

  // ---- read addressing (R7-verified): frag f rows wm*64+f*16+(l&15),
  // k-chunk l>>4; macro-row hl = (l&15)>>1; granule position gr^hl.
  const int hl = (l & 15) >> 1;
  const int gr = (((l & 1) << 2) | (l >> 4)) ^ hl;
  const unsigned aBase = (unsigned)(uintptr_t)(lds_s*)&Alds[0][0];
  const unsigned bBase = (unsigned)(uintptr_t)(lds_s*)&Blds[0][0];
  unsigned ardA[3], ardB[3];
#pragma unroll
  for (int bI = 0; bI < 3; ++bI) {
    ardA[bI] = aBase + bI * 8192u + (unsigned)(wm * 4096 + hl * 128 + gr * 16);
    ardB[bI] = bBase + bI * 8192u + (unsigned)(wn * 4096 + hl * 128 + gr * 16);
  }

  i32x4 a[4], b[4];
  f32x4 acc[4][4];
  const f32x4 zero = {0.f, 0.f, 0.f, 0.f};
#pragma unroll
  for (int i = 0; i < 4; ++i)
#pragma unroll
    for (int j = 0; j < 4; ++j) acc[i][j] = zero;

  auto mfmaAll = [&]() {
#pragma unroll
    for (int f = 0; f < 4; ++f)
#pragma unroll
      for (int fn = 0; fn < 4; ++fn)
        acc[f][fn] = __builtin_amdgcn_mfma_f32_16x16x32_bf16(
            asbf(a[f]), asbf(b[fn]), acc[f][fn], 0, 0, 0);
  };

#define RD_TILE(C) do {                                                   \
    DSRD(a[0], ardA[C], "0");    DSRD(a[1], ardA[C], "1024");             \
    DSRD(a[2], ardA[C], "2048"); DSRD(a[3], ardA[C], "3072");             \
    DSRD(b[0], ardB[C], "0");    DSRD(b[1], ardB[C], "1024");             \
    DSRD(b[2], ardB[C], "2048"); DSRD(b[3], ardB[C], "3072");             \
  } while (0)

#define STAGE(S, KS) do {                                                 \
    stageA(S, 0, KS); stageA(S, 1, KS);                                   \
    stageB(S, 0, KS); stageB(S, 1, KS);                                   \
  } while (0)

  // TILE(C=u%3, S=(u+2)%3, u): clamped staging keeps vmcnt counts uniform.
#define TILE(C, S, u) do {                                                \
    const int _ks = ((u) + 2 < NT ? (u) + 2 : NT - 1) * 32;               \
    STAGE(S, _ks);                                                        \
    RD_TILE(C);                                                           \
    LGKM0;                                                                \
    __builtin_amdgcn_s_setprio(1); mfmaAll(); __builtin_amdgcn_s_setprio(0); \
    SB0;                                                                  \
    asm volatile("s_waitcnt vmcnt(4)" ::: "memory");                      \
    PBAR;                                                                 \
  } while (0)

  // prologue: stage tiles 0,1 (8 loads); drain tile 0's (vmcnt(4)); barrier
  STAGE(0, 0); STAGE(1, 32);
  asm volatile("s_waitcnt vmcnt(4)" ::: "memory");
  PBAR;

  for (int t = 0; t < NT - 1; t += 3) {   // t = 0,3,...,60 -> tiles 0..62
    TILE(0, 2, t);
    TILE(1, 0, t + 1);
    TILE(2, 1, t + 2);
  }
  // tile 63 (buf 0): staged @61, drained by end-of-62 vmcnt(4)+barrier
  RD_TILE(0);
  LGKM0;
  __builtin_amdgcn_s_setprio(1); mfmaAll(); __builtin_amdgcn_s_setprio(0);
  SB0;
#undef TILE
#undef STAGE
#undef RD_TILE
  asm volatile("s_waitcnt vmcnt(0) lgkmcnt(0)" ::: "memory");

  // epilogue: C/D layout col=lane&15, row=(lane>>4)*4+i  [R1/R7-verified]
  const int r16 = l & 15, r4base = (l >> 4) * 4;
  if (EPI == 0) {
    float bb[4];
#pragma unroll
    for (int fn = 0; fn < 4; ++fn) bb[fn] = bias[n0 + wn * 64 + fn * 16 + r16];
#pragma unroll
    for (int fm = 0; fm < 4; ++fm) {
      const int grow = m0 + wm * 64 + fm * 16 + r4base;
#pragma unroll
      for (int fn = 0; fn < 4; ++fn) {
        const int gcol = n0 + wn * 64 + fn * 16 + r16;
        f32x4 v = acc[fm][fn];
#pragma unroll
        for (int i = 0; i < 4; ++i) {
          float z = v[i] + bb[fn];
          float ge = 0.5f * z * (1.0f + erff(z * 0.70710678118654752f));
          Hout[(size_t)(grow + i) * K + gcol] = __float2bfloat16(ge);
        }
      }
    }
  } else {
    float bb[4];
#pragma unroll
    for (int fn = 0; fn < 4; ++fn) bb[fn] = bias[n0 + wn * 64 + fn * 16 + r16];
#pragma unroll
    for (int fm = 0; fm < 4; ++fm) {
      const int grow = m0 + wm * 64 + fm * 16 + r4base;
      int rid[4];
#pragma unroll
      for (int i = 0; i < 4; ++i) rid[i] = rowid[grow + i];
#pragma unroll
      for (int fn = 0; fn < 4; ++fn) {
        const int gcol = n0 + wn * 64 + fn * 16 + r16;
        f32x4 v = acc[fm][fn];
#pragma unroll
        for (int i = 0; i < 4; ++i) {
          if (rid[i] >= 0) {
            const size_t o = (size_t)rid[i] * K + gcol;
            Out[o] = resid[o] + v[i] + bb[fn];
          }
        }
      }
    }
  }
}

// ---------------------------------------------------------------------------
extern "C" void kernel_launch(void* const* d_in, const int* in_sizes, int n_in,
                              void* d_out, int out_size, void* d_ws, size_t ws_size,
                              hipStream_t stream) {
  const float* hidden = (const float*)d_in[0];
  const int*   tt     = (const int*)d_in[1];
  const float* gamma  = (const float*)d_in[2];
  const float* beta   = (const float*)d_in[3];
  const float* tw1    = (const float*)d_in[4];
  const float* tb1    = (const float*)d_in[5];
  const float* tw2    = (const float*)d_in[6];
  const float* tb2    = (const float*)d_in[7];
  const float* iw1    = (const float*)d_in[8];
  const float* ib1    = (const float*)d_in[9];
  const float* iw2    = (const float*)d_in[10];
  const float* ib2    = (const float*)d_in[11];
  float* out = (float*)d_out;

  const int T = in_sizes[1];          // 8192 tokens
  const int K = H_DIM;
  const int maxtiles = T / 128 + 2;   // groups padded to 128 -> 66 tiles
  const int maxrows = maxtiles * 128;

  char* ws = (char*)d_ws;
  int* ctrl  = (int*)(ws);
  int* pos   = (int*)(ws + 4096);
  int* rowid = (int*)(ws + 65536);
  const size_t WOFF = 131072;
  const size_t WSZ = (size_t)K * K * sizeof(__hip_bfloat16);
  __hip_bfloat16* tw1T = (__hip_bfloat16*)(ws + WOFF);
  __hip_bfloat16* tw2T = (__hip_bfloat16*)(ws + WOFF + WSZ);
  __hip_bfloat16* iw1T = (__hip_bfloat16*)(ws + WOFF + 2 * WSZ);
  __hip_bfloat16* iw2T = (__hip_bfloat16*)(ws + WOFF + 3 * WSZ);
  __hip_bfloat16* xg   = (__hip_bfloat16*)(ws + WOFF + 4 * WSZ);
  __hip_bfloat16* hb   = xg + (size_t)maxrows * K;

  hipMemsetAsync(xg, 0, (size_t)maxrows * K * sizeof(__hip_bfloat16), stream);

  partition_kernel<<<1, 256, 0, stream>>>(tt, T, ctrl, pos, rowid);

  dim3 tg(K / 32, K / 32);
  transpose_to_bf16<<<tg, 256, 0, stream>>>(tw1, tw1T);
  transpose_to_bf16<<<tg, 256, 0, stream>>>(tw2, tw2T);
  transpose_to_bf16<<<tg, 256, 0, stream>>>(iw1, iw1T);
  transpose_to_bf16<<<tg, 256, 0, stream>>>(iw2, iw2T);

  ln_scatter_kernel<<<T, 256, 0, stream>>>(hidden, gamma, beta, pos, xg);

  const int nblk = maxtiles * (K / 128);   // 66 * 16 = 1056
  gemmk<0><<<nblk, 256, 0, stream>>>(xg, tw1T, iw1T, tb1, ib1, ctrl, rowid,
                                     hb, nullptr, nullptr);
  gemmk<1><<<nblk, 256, 0, stream>>>(hb, tw2T, iw2T, tb2, ib2, ctrl, rowid,
                                     nullptr, hidden, out);
}

// Round 11
// 326.133 us; speedup vs baseline: 1.0030x; 1.0030x over previous
//
#include <hip/hip_runtime.h>
#include <hip/hip_bf16.h>

// ---------------------------------------------------------------------------
// MVoT token processor: out = hidden + MLP_{type}(LN(hidden)), type in {0,1}
// Partition tokens by type -> dense bf16 MFMA GEMMs (half the reference FLOPs).
// GEMM (R11 = R7 loop, bigger block): 128x256 block, 8 waves of 64x64
// (R7's exact per-wave fragment math), BK=32, 2 LDS bufs (48 KiB), ~124
// regs/thread -> 2 blocks/CU (16 waves, vs R7's 10). Grid 528 = 66 m-tiles
// x 8 n-panels; XCD n owns panel n -> 1 MB B L2-resident per XCD; per-FLOP
// LDS traffic 0.67x of R7, B HBM refetch halved.
// ---------------------------------------------------------------------------

#define H_DIM 2048

typedef __attribute__((ext_vector_type(8))) short s16x8;   // 8 bf16 (4 VGPRs)
typedef __attribute__((ext_vector_type(4))) float f32x4;   // MFMA accumulator
typedef __attribute__((ext_vector_type(4))) int   i32x4;   // asm ds_read dst

typedef __attribute__((address_space(1))) const unsigned int gu32;
typedef __attribute__((address_space(3))) unsigned int lu32;
typedef __attribute__((address_space(3))) short lds_s;

__device__ __forceinline__ void load_lds16(const void* g, void* l) {
  // async global->LDS, 16B per lane; LDS dest = wave-uniform base + lane*16
  __builtin_amdgcn_global_load_lds((gu32*)g, (lu32*)l, 16, 0, 0);
}

__device__ __forceinline__ s16x8 asbf(i32x4 v) {
  union { i32x4 i; s16x8 s; } u; u.i = v; return u.s;
}

// ---------------------------------------------------------------------------
// Partition: stable scan of token_type_ids. text (type==0) first, padded to
// 128 rows (BM), then image (type==1), padded. Single block, deterministic.
// ctrl: [0]=Mt [1]=Mt_pad [2]=Mi [3]=Mi_pad [4]=total_rows
// ---------------------------------------------------------------------------
__global__ __launch_bounds__(256) void partition_kernel(
    const int* __restrict__ tt, int T, int* __restrict__ ctrl,
    int* __restrict__ pos, int* __restrict__ rowid) {
  __shared__ int psum[256];
  const int tid = threadIdx.x;
  const int npt = T >> 8;
  const int base = tid * npt;
  int cnt = 0;
  for (int i = 0; i < npt; ++i) cnt += (tt[base + i] == 0);
  psum[tid] = cnt;
  __syncthreads();
  for (int off = 1; off < 256; off <<= 1) {
    int v = psum[tid];
    int add = (tid >= off) ? psum[tid - off] : 0;
    __syncthreads();
    psum[tid] = v + add;
    __syncthreads();
  }
  const int Mt = psum[255];
  const int Mt_pad = (Mt + 127) & ~127;
  int tpos = psum[tid] - cnt;
  int ipos = base - tpos;
  for (int i = 0; i < npt; ++i) {
    const int tok = base + i;
    int p;
    if (tt[tok] == 0) p = tpos++;
    else              p = Mt_pad + ipos++;
    pos[tok] = p;
    rowid[p] = tok;
  }
  const int Mi = T - Mt;
  const int Mi_pad = (Mi + 127) & ~127;
  for (int g = Mt + tid; g < Mt_pad; g += 256) rowid[g] = -1;
  for (int g = Mt_pad + Mi + tid; g < Mt_pad + Mi_pad; g += 256) rowid[g] = -1;
  if (tid == 0) {
    ctrl[0] = Mt; ctrl[1] = Mt_pad; ctrl[2] = Mi; ctrl[3] = Mi_pad;
    ctrl[4] = Mt_pad + Mi_pad;
  }
}

// ---------------------------------------------------------------------------
// Weight transpose + fp32->bf16: W[k][n] -> WT[n][k] (B^T layout for GEMM)
// ---------------------------------------------------------------------------
__global__ __launch_bounds__(256) void transpose_to_bf16(
    const float* __restrict__ W, __hip_bfloat16* __restrict__ WT) {
  __shared__ float tile[32][33];
  const int bx = blockIdx.x, by = blockIdx.y;
  const int tid = threadIdx.x;
  const int r = tid >> 3, c4 = (tid & 7) * 4;
  const float4 v = *(const float4*)(W + (size_t)(by * 32 + r) * H_DIM + bx * 32 + c4);
  tile[r][c4 + 0] = v.x; tile[r][c4 + 1] = v.y;
  tile[r][c4 + 2] = v.z; tile[r][c4 + 3] = v.w;
  __syncthreads();
  union { ushort u[4]; ushort4 v4; } pk;
#pragma unroll
  for (int j = 0; j < 4; ++j) {
    __hip_bfloat16 h = __float2bfloat16(tile[c4 + j][r]);
    pk.u[j] = *(const ushort*)&h;
  }
  *(ushort4*)(WT + (size_t)(bx * 32 + r) * H_DIM + by * 32 + c4) = pk.v4;
}

// ---------------------------------------------------------------------------
// LayerNorm (fp32) -> bf16, scatter row to its gathered position.
// ---------------------------------------------------------------------------
__global__ __launch_bounds__(256) void ln_scatter_kernel(
    const float* __restrict__ X, const float* __restrict__ gamma,
    const float* __restrict__ beta, const int* __restrict__ pos,
    __hip_bfloat16* __restrict__ XG) {
  const int t = blockIdx.x, tid = threadIdx.x;
  const float* row = X + (size_t)t * H_DIM;
  float x[8];
  {
    float4 v0 = *(const float4*)(row + tid * 8);
    float4 v1 = *(const float4*)(row + tid * 8 + 4);
    x[0] = v0.x; x[1] = v0.y; x[2] = v0.z; x[3] = v0.w;
    x[4] = v1.x; x[5] = v1.y; x[6] = v1.z; x[7] = v1.w;
  }
  float s = 0.f, q = 0.f;
#pragma unroll
  for (int j = 0; j < 8; ++j) { s += x[j]; q += x[j] * x[j]; }
#pragma unroll
  for (int off = 32; off > 0; off >>= 1) {
    s += __shfl_down(s, off);
    q += __shfl_down(q, off);
  }
  __shared__ float ls[4], lq[4];
  if ((tid & 63) == 0) { ls[tid >> 6] = s; lq[tid >> 6] = q; }
  __syncthreads();
  const float S = ls[0] + ls[1] + ls[2] + ls[3];
  const float Q = lq[0] + lq[1] + lq[2] + lq[3];
  const float mu = S * (1.0f / H_DIM);
  const float var = Q * (1.0f / H_DIM) - mu * mu;
  const float rstd = rsqrtf(var + 1e-12f);
  const int p = pos[t];
  float4 g0 = *(const float4*)(gamma + tid * 8);
  float4 g1 = *(const float4*)(gamma + tid * 8 + 4);
  float4 b0 = *(const float4*)(beta + tid * 8);
  float4 b1 = *(const float4*)(beta + tid * 8 + 4);
  float g[8] = {g0.x, g0.y, g0.z, g0.w, g1.x, g1.y, g1.z, g1.w};
  float b[8] = {b0.x, b0.y, b0.z, b0.w, b1.x, b1.y, b1.z, b1.w};
  union { ushort u[8]; int4 v; } pk;
#pragma unroll
  for (int j = 0; j < 8; ++j) {
    float y = (x[j] - mu) * rstd * g[j] + b[j];
    __hip_bfloat16 h = __float2bfloat16(y);
    pk.u[j] = *(const ushort*)&h;
  }
  *(int4*)(XG + (size_t)p * H_DIM + tid * 8) = pk.v;
}

// --- asm helpers for the GEMM inner loop -----------------------------------
#define DSRD(dst, addr, OFF) \
  asm volatile("ds_read_b128 %0, %1 offset:" OFF : "=v"(dst) : "v"(addr))
#define PBAR asm volatile("s_barrier" ::: "memory")
#define SB0  __builtin_amdgcn_sched_barrier(0)
#define LGKM0 do { \
  asm volatile("s_waitcnt lgkmcnt(0)" ::: "memory"); SB0; } while (0)
#define VM0 asm volatile("s_waitcnt vmcnt(0)" ::: "memory")

// ---------------------------------------------------------------------------
// R11 GEMM: 128x256 block, BK=32. 512 thr = 8 waves (wm=w>>2 in {0,1},
// wn=w&3 in {0..3}), per-wave 64x64 = acc[4][4] frags of 16x16x32 — R7's
// exact per-wave math. LDS 48 KiB: Alds[2][4096] (64 macro-rows),
// Blds[2][8192] (128 macro-rows). Macro-row mr packs rows {2mr,2mr+1} x 32 k
// as 8 granules of 8 elems, granule g at position g^(mr&7) (conflict-free,
// R7-verified). Staging = pre-swizzled GLOBAL source + linear LDS dest:
// 8 waves x {1 A call + 2 B calls} cover the tile.
// Loop (R7-verbatim): stage(next)->ds_read->lgkm0->16 MFMA->vm0->barrier.
// ~124 unified regs/thread -> 4 waves/SIMD -> 2 blocks/CU co-resident.
// ---------------------------------------------------------------------------
template <int EPI>
__global__ __launch_bounds__(512, 2) void gemmk(
    const __hip_bfloat16* __restrict__ A,
    const __hip_bfloat16* __restrict__ WTt, const __hip_bfloat16* __restrict__ WTi,
    const float* __restrict__ bt, const float* __restrict__ bi,
    const int* __restrict__ ctrl, const int* __restrict__ rowid,
    __hip_bfloat16* __restrict__ Hout,
    const float* __restrict__ resid, float* __restrict__ Out) {
  constexpr int K = H_DIM;
  constexpr int NT = K / 32;            // 64 K-tiles
  const int Mt_pad = ctrl[1];
  const int total = ctrl[4];
  // 528 blocks = 66 m-tiles x 8 n-panels. XCD x (bid&7) owns n-panel x:
  // its 256-col B panel (1 MB) stays L2-resident for all 66 m-tiles.
  const int bid = blockIdx.x;
  const int m0 = (bid >> 3) * 128;
  const int n0 = (bid & 7) * 256;
  if (m0 >= total) return;
  const bool is_text = (m0 < Mt_pad);
  const short* Ag = (const short*)A;
  const short* Bg = (const short*)(is_text ? WTt : WTi);
  const float* bias = is_text ? bt : bi;

  __shared__ __align__(16) short Alds[2][4096];   // [buf][64 mr * 64] = 8 KiB
  __shared__ __align__(16) short Blds[2][8192];   // [buf][128 mr * 64] = 16 KiB

  const int tid = threadIdx.x;
  const int w = tid >> 6, l = tid & 63;           // 8 waves
  const int wm = w >> 2, wn = w & 3;

  // ---- staging lane constants (pre-swizzled global source, R7-verified)
  const int srow8 = l >> 3;               // macro-row within this wave's 8
  const int sg = (l & 7) ^ srow8;         // granule fetched for position l&7
  const int sRowAdj = sg >> 2;            // row parity within macro-row
  const int sKAdj = (sg & 3) * 8;         // k offset 0..24

  // A: 64 macro-rows, wave w stages mr = w*8+srow8 (1 call)
  auto stageA = [&](int bI, int kk) {
    const int mr = w * 8 + srow8;
    const short* src = Ag + (size_t)(m0 + mr * 2 + sRowAdj) * K + kk + sKAdj;
    load_lds16(src, &Alds[bI][(w * 8) * 64]);
  };
  // B: 128 macro-rows (256 cols), wave w stages mr = c2*64 + w*8 + srow8
  auto stageB = [&](int bI, int c2, int kk) {
    const int mr = c2 * 64 + w * 8 + srow8;
    const short* src = Bg + (size_t)(n0 + mr * 2 + sRowAdj) * K + kk + sKAdj;
    load_lds16(src, &Blds[bI][(c2 * 64 + w * 8) * 64]);
  };

  // ---- read addressing (R7-verified macro-row swizzle)
  // A frag f: macro-row wm*32 + f*8 + hl -> byte wm*4096 + f*1024 + hl*128
  // B frag f: macro-row wn*32 + f*8 + hl -> byte wn*4096 + f*1024 + hl*128
  // granule position = gr ^ hl (mr&7 == hl in both cases), 16B each.
  const int hl = (l & 15) >> 1;
  const int gr = (((l & 1) << 2) | (l >> 4)) ^ hl;
  const unsigned aBase = (unsigned)(uintptr_t)(lds_s*)&Alds[0][0];
  const unsigned bBase = (unsigned)(uintptr_t)(lds_s*)&Blds[0][0];
  unsigned ardA[2], ardB[2];
#pragma unroll
  for (int bI = 0; bI < 2; ++bI) {
    ardA[bI] = aBase + bI * 8192u  + (unsigned)(wm * 4096 + hl * 128 + gr * 16);
    ardB[bI] = bBase + bI * 16384u + (unsigned)(wn * 4096 + hl * 128 + gr * 16);
  }

  i32x4 a[4], b[4];
  f32x4 acc[4][4];
  const f32x4 zero = {0.f, 0.f, 0.f, 0.f};
#pragma unroll
  for (int i = 0; i < 4; ++i)
#pragma unroll
    for (int j = 0; j < 4; ++j) acc[i][j] = zero;

#define RD_TILE(C) do {                                                   \
    DSRD(a[0], ardA[C], "0");    DSRD(a[1], ardA[C], "1024");             \
    DSRD(a[2], ardA[C], "2048"); DSRD(a[3], ardA[C], "3072");             \
    DSRD(b[0], ardB[C], "0");    DSRD(b[1], ardB[C], "1024");             \
    DSRD(b[2], ardB[C], "2048"); DSRD(b[3], ardB[C], "3072");             \
  } while (0)

  // prologue: stage tile 0 into buf 0
  stageA(0, 0);
  stageB(0, 0, 0); stageB(0, 1, 0);
  VM0;
  PBAR;

  for (int t = 0; t < NT; ++t) {
    const int c = t & 1;
    const int kn = (t + 1 < NT ? t + 1 : NT - 1) * 32;
    // issue next-tile staging first (HBM/L2 latency hides under reads+MFMA)
    stageA(c ^ 1, kn);
    stageB(c ^ 1, 0, kn); stageB(c ^ 1, 1, kn);
    RD_TILE(c);
    LGKM0;
    __builtin_amdgcn_s_setprio(1);
#pragma unroll
    for (int f = 0; f < 4; ++f)
#pragma unroll
      for (int fn = 0; fn < 4; ++fn)
        acc[f][fn] = __builtin_amdgcn_mfma_f32_16x16x32_bf16(
            asbf(a[f]), asbf(b[fn]), acc[f][fn], 0, 0, 0);
    __builtin_amdgcn_s_setprio(0);
    SB0;
    VM0;   // this wave's staging landed
    PBAR;  // all waves: reads of buf c retired + staging of buf c^1 landed
  }
#undef RD_TILE

  // epilogue: C/D layout col=lane&15, row=(lane>>4)*4+i  [R1/R7-verified]
  const int r16 = l & 15, r4base = (l >> 4) * 4;
  if (EPI == 0) {
    float bb[4];
#pragma unroll
    for (int fn = 0; fn < 4; ++fn) bb[fn] = bias[n0 + wn * 64 + fn * 16 + r16];
#pragma unroll
    for (int fm = 0; fm < 4; ++fm) {
      const int grow = m0 + wm * 64 + fm * 16 + r4base;
#pragma unroll
      for (int fn = 0; fn < 4; ++fn) {
        const int gcol = n0 + wn * 64 + fn * 16 + r16;
        f32x4 v = acc[fm][fn];
#pragma unroll
        for (int i = 0; i < 4; ++i) {
          float z = v[i] + bb[fn];
          float ge = 0.5f * z * (1.0f + erff(z * 0.70710678118654752f));
          Hout[(size_t)(grow + i) * K + gcol] = __float2bfloat16(ge);
        }
      }
    }
  } else {
    float bb[4];
#pragma unroll
    for (int fn = 0; fn < 4; ++fn) bb[fn] = bias[n0 + wn * 64 + fn * 16 + r16];
#pragma unroll
    for (int fm = 0; fm < 4; ++fm) {
      const int grow = m0 + wm * 64 + fm * 16 + r4base;
      int rid[4];
#pragma unroll
      for (int i = 0; i < 4; ++i) rid[i] = rowid[grow + i];
#pragma unroll
      for (int fn = 0; fn < 4; ++fn) {
        const int gcol = n0 + wn * 64 + fn * 16 + r16;
        f32x4 v = acc[fm][fn];
#pragma unroll
        for (int i = 0; i < 4; ++i) {
          if (rid[i] >= 0) {
            const size_t o = (size_t)rid[i] * K + gcol;
            Out[o] = resid[o] + v[i] + bb[fn];
          }
        }
      }
    }
  }
}

// ---------------------------------------------------------------------------
extern "C" void kernel_launch(void* const* d_in, const int* in_sizes, int n_in,
                              void* d_out, int out_size, void* d_ws, size_t ws_size,
                              hipStream_t stream) {
  const float* hidden = (const float*)d_in[0];
  const int*   tt     = (const int*)d_in[1];
  const float* gamma  = (const float*)d_in[2];
  const float* beta   = (const float*)d_in[3];
  const float* tw1    = (const float*)d_in[4];
  const float* tb1    = (const float*)d_in[5];
  const float* tw2    = (const float*)d_in[6];
  const float* tb2    = (const float*)d_in[7];
  const float* iw1    = (const float*)d_in[8];
  const float* ib1    = (const float*)d_in[9];
  const float* iw2    = (const float*)d_in[10];
  const float* ib2    = (const float*)d_in[11];
  float* out = (float*)d_out;

  const int T = in_sizes[1];          // 8192 tokens
  const int K = H_DIM;
  const int maxtiles = T / 128 + 2;   // groups padded to 128 -> 66 m-tiles
  const int maxrows = maxtiles * 128;

  char* ws = (char*)d_ws;
  int* ctrl  = (int*)(ws);
  int* pos   = (int*)(ws + 4096);
  int* rowid = (int*)(ws + 65536);
  const size_t WOFF = 131072;
  const size_t WSZ = (size_t)K * K * sizeof(__hip_bfloat16);
  __hip_bfloat16* tw1T = (__hip_bfloat16*)(ws + WOFF);
  __hip_bfloat16* tw2T = (__hip_bfloat16*)(ws + WOFF + WSZ);
  __hip_bfloat16* iw1T = (__hip_bfloat16*)(ws + WOFF + 2 * WSZ);
  __hip_bfloat16* iw2T = (__hip_bfloat16*)(ws + WOFF + 3 * WSZ);
  __hip_bfloat16* xg   = (__hip_bfloat16*)(ws + WOFF + 4 * WSZ);
  __hip_bfloat16* hb   = xg + (size_t)maxrows * K;

  hipMemsetAsync(xg, 0, (size_t)maxrows * K * sizeof(__hip_bfloat16), stream);

  partition_kernel<<<1, 256, 0, stream>>>(tt, T, ctrl, pos, rowid);

  dim3 tg(K / 32, K / 32);
  transpose_to_bf16<<<tg, 256, 0, stream>>>(tw1, tw1T);
  transpose_to_bf16<<<tg, 256, 0, stream>>>(tw2, tw2T);
  transpose_to_bf16<<<tg, 256, 0, stream>>>(iw1, iw1T);
  transpose_to_bf16<<<tg, 256, 0, stream>>>(iw2, iw2T);

  ln_scatter_kernel<<<T, 256, 0, stream>>>(hidden, gamma, beta, pos, xg);

  const int nblk = maxtiles * (K / 256);   // 66 * 8 = 528
  gemmk<0><<<nblk, 512, 0, stream>>>(xg, tw1T, iw1T, tb1, ib1, ctrl, rowid,
                                     hb, nullptr, nullptr);
  gemmk<1><<<nblk, 512, 0, stream>>>(hb, tw2T, iw2T, tb2, ib2, ctrl, rowid,
                                     nullptr, hidden, out);
}

// Round 12
// 267.270 us; speedup vs baseline: 1.2239x; 1.2202x over previous
//
#include <hip/hip_runtime.h>
#include <hip/hip_bf16.h>

// ---------------------------------------------------------------------------
// MVoT token processor: out = hidden + MLP_{type}(LN(hidden)), type in {0,1}
// R12: grid-quantization fix. R4's 256x256 BK=64 kernel runs ~78us solo but
// 264 tiles on 256 CUs at 1 blk/CU forced a 2-round makespan (156us). Now:
// 256 full tiles (m-rows 0..31, EXACTLY 1/CU) + tail m-rows (8192..8703) as
// 128 split-K (K/4) 128x256 blocks (R11 math) writing fp32 partials, summed
// by a tiny combine kernel. Makespan ~= 78 + ~12 us.
// ---------------------------------------------------------------------------

#define H_DIM 2048
#define FULLROWS 8192
#define TAILROWS 512

typedef __attribute__((ext_vector_type(8))) short s16x8;   // 8 bf16 (4 VGPRs)
typedef __attribute__((ext_vector_type(4))) float f32x4;   // MFMA accumulator
typedef __attribute__((ext_vector_type(4))) int   i32x4;   // asm ds_read dst

typedef __attribute__((address_space(1))) const unsigned int gu32;
typedef __attribute__((address_space(3))) unsigned int lu32;
typedef __attribute__((address_space(3))) short lds_s;

__device__ __forceinline__ void load_lds16(const void* g, void* l) {
  __builtin_amdgcn_global_load_lds((gu32*)g, (lu32*)l, 16, 0, 0);
}

__device__ __forceinline__ s16x8 asbf(i32x4 v) {
  union { i32x4 i; s16x8 s; } u; u.i = v; return u.s;
}

// ---------------------------------------------------------------------------
// Partition (R2-verified): text first, each group padded to 256 rows.
// ctrl: [0]=Mt [1]=Mt_pad [2]=Mi [3]=Mi_pad [4]=total_rows
// ---------------------------------------------------------------------------
__global__ __launch_bounds__(256) void partition_kernel(
    const int* __restrict__ tt, int T, int* __restrict__ ctrl,
    int* __restrict__ pos, int* __restrict__ rowid) {
  __shared__ int psum[256];
  const int tid = threadIdx.x;
  const int npt = T >> 8;
  const int base = tid * npt;
  int cnt = 0;
  for (int i = 0; i < npt; ++i) cnt += (tt[base + i] == 0);
  psum[tid] = cnt;
  __syncthreads();
  for (int off = 1; off < 256; off <<= 1) {
    int v = psum[tid];
    int add = (tid >= off) ? psum[tid - off] : 0;
    __syncthreads();
    psum[tid] = v + add;
    __syncthreads();
  }
  const int Mt = psum[255];
  const int Mt_pad = (Mt + 255) & ~255;
  int tpos = psum[tid] - cnt;
  int ipos = base - tpos;
  for (int i = 0; i < npt; ++i) {
    const int tok = base + i;
    int p;
    if (tt[tok] == 0) p = tpos++;
    else              p = Mt_pad + ipos++;
    pos[tok] = p;
    rowid[p] = tok;
  }
  const int Mi = T - Mt;
  const int Mi_pad = (Mi + 255) & ~255;
  for (int g = Mt + tid; g < Mt_pad; g += 256) rowid[g] = -1;
  for (int g = Mt_pad + Mi + tid; g < Mt_pad + Mi_pad; g += 256) rowid[g] = -1;
  // pad rowid out to the static 8704-row region
  for (int g = Mt_pad + Mi_pad + tid; g < FULLROWS + TAILROWS; g += 256)
    rowid[g] = -1;
  if (tid == 0) {
    ctrl[0] = Mt; ctrl[1] = Mt_pad; ctrl[2] = Mi; ctrl[3] = Mi_pad;
    ctrl[4] = Mt_pad + Mi_pad;
  }
}

// ---------------------------------------------------------------------------
// Weight transpose + fp32->bf16: W[k][n] -> WT[n][k] (B^T layout)
// ---------------------------------------------------------------------------
__global__ __launch_bounds__(256) void transpose_to_bf16(
    const float* __restrict__ W, __hip_bfloat16* __restrict__ WT) {
  __shared__ float tile[32][33];
  const int bx = blockIdx.x, by = blockIdx.y;
  const int tid = threadIdx.x;
  const int r = tid >> 3, c4 = (tid & 7) * 4;
  const float4 v = *(const float4*)(W + (size_t)(by * 32 + r) * H_DIM + bx * 32 + c4);
  tile[r][c4 + 0] = v.x; tile[r][c4 + 1] = v.y;
  tile[r][c4 + 2] = v.z; tile[r][c4 + 3] = v.w;
  __syncthreads();
  union { ushort u[4]; ushort4 v4; } pk;
#pragma unroll
  for (int j = 0; j < 4; ++j) {
    __hip_bfloat16 h = __float2bfloat16(tile[c4 + j][r]);
    pk.u[j] = *(const ushort*)&h;
  }
  *(ushort4*)(WT + (size_t)(bx * 32 + r) * H_DIM + by * 32 + c4) = pk.v4;
}

// ---------------------------------------------------------------------------
// LayerNorm (fp32) -> bf16, scatter row to its gathered position.
// ---------------------------------------------------------------------------
__global__ __launch_bounds__(256) void ln_scatter_kernel(
    const float* __restrict__ X, const float* __restrict__ gamma,
    const float* __restrict__ beta, const int* __restrict__ pos,
    __hip_bfloat16* __restrict__ XG) {
  const int t = blockIdx.x, tid = threadIdx.x;
  const float* row = X + (size_t)t * H_DIM;
  float x[8];
  {
    float4 v0 = *(const float4*)(row + tid * 8);
    float4 v1 = *(const float4*)(row + tid * 8 + 4);
    x[0] = v0.x; x[1] = v0.y; x[2] = v0.z; x[3] = v0.w;
    x[4] = v1.x; x[5] = v1.y; x[6] = v1.z; x[7] = v1.w;
  }
  float s = 0.f, q = 0.f;
#pragma unroll
  for (int j = 0; j < 8; ++j) { s += x[j]; q += x[j] * x[j]; }
#pragma unroll
  for (int off = 32; off > 0; off >>= 1) {
    s += __shfl_down(s, off);
    q += __shfl_down(q, off);
  }
  __shared__ float ls[4], lq[4];
  if ((tid & 63) == 0) { ls[tid >> 6] = s; lq[tid >> 6] = q; }
  __syncthreads();
  const float S = ls[0] + ls[1] + ls[2] + ls[3];
  const float Q = lq[0] + lq[1] + lq[2] + lq[3];
  const float mu = S * (1.0f / H_DIM);
  const float var = Q * (1.0f / H_DIM) - mu * mu;
  const float rstd = rsqrtf(var + 1e-12f);
  const int p = pos[t];
  float4 g0 = *(const float4*)(gamma + tid * 8);
  float4 g1 = *(const float4*)(gamma + tid * 8 + 4);
  float4 b0 = *(const float4*)(beta + tid * 8);
  float4 b1 = *(const float4*)(beta + tid * 8 + 4);
  float g[8] = {g0.x, g0.y, g0.z, g0.w, g1.x, g1.y, g1.z, g1.w};
  float b[8] = {b0.x, b0.y, b0.z, b0.w, b1.x, b1.y, b1.z, b1.w};
  union { ushort u[8]; int4 v; } pk;
#pragma unroll
  for (int j = 0; j < 8; ++j) {
    float y = (x[j] - mu) * rstd * g[j] + b[j];
    __hip_bfloat16 h = __float2bfloat16(y);
    pk.u[j] = *(const ushort*)&h;
  }
  *(int4*)(XG + (size_t)p * H_DIM + tid * 8) = pk.v;
}

// --- asm helpers -----------------------------------------------------------
#define DSRD(dst, addr, OFF) \
  asm volatile("ds_read_b128 %0, %1 offset:" OFF : "=v"(dst) : "v"(addr))
#define PBAR asm volatile("s_barrier" ::: "memory")
#define SB0  __builtin_amdgcn_sched_barrier(0)
#define LGKM0 do { \
  asm volatile("s_waitcnt lgkmcnt(0)" ::: "memory"); SB0; } while (0)
#define VM0 asm volatile("s_waitcnt vmcnt(0)" ::: "memory")

__device__ __forceinline__ float gelu_exact(float z) {
  return 0.5f * z * (1.0f + erff(z * 0.70710678118654752f));
}

// ---------------------------------------------------------------------------
// Unified GEMM, grid = 384 x 512 thr:
//  bid < 256: FULL path (R4-verified): 256x256 tile, BK=64, 8 waves of
//    128x64 (acc[8][4]), 4 asm phases/K-tile, vmcnt(4), XOR-swizzled LDS
//    (128 KiB). m0=(bid>>3)*256 in [0,8192): always < total, never straddles
//    the 256-aligned group boundary. Direct epilogue (EPI0 GELU / EPI1 resid).
//  bid >= 256: TAIL path (R11-verified): 128x256 tile, BK=32, 8 waves of
//    64x64 (acc[4][4]), K-range = kp*512..+512 (kp=tb&3), rows 8192..8703,
//    writes raw fp32 partials to pp[kp][512][2048]. Tail blocks dispatch
//    after the full wave and fill in behind it (~12us each).
// ---------------------------------------------------------------------------
template <int EPI>
__global__ __launch_bounds__(512, 2) void gemmk(
    const __hip_bfloat16* __restrict__ A,
    const __hip_bfloat16* __restrict__ WTt, const __hip_bfloat16* __restrict__ WTi,
    const float* __restrict__ bt, const float* __restrict__ bi,
    const int* __restrict__ ctrl, const int* __restrict__ rowid,
    __hip_bfloat16* __restrict__ Hout,
    const float* __restrict__ resid, float* __restrict__ Out,
    float* __restrict__ pp) {
  constexpr int K = H_DIM;
  const int Mt_pad = ctrl[1];

  __shared__ __align__(16) char smem[131072];
  const unsigned sBase = (unsigned)(uintptr_t)(lds_s*)smem;

  const int tid = threadIdx.x;
  const int w = tid >> 6, l = tid & 63;
  const int bid = blockIdx.x;

  // staging lane constants (shared by both paths; R4/R11-verified)
  const int srow8 = l >> 3;
  const int sg = (l & 7) ^ srow8;
  const int r16 = l & 15;
  const int r4base = (l >> 4) * 4;
  // read lane constants
  const int hl = (l & 15) >> 1;
  const int gr = (((l & 1) << 2) | (l >> 4)) ^ hl;

  if (bid < 256) {
    // ===================== FULL PATH (R4 verbatim) ========================
    constexpr int NT = K / 64;          // 32 K-tiles
    const int m0 = (bid >> 3) * 256;
    const int n0 = (bid & 7) * 256;
    const bool is_text = (m0 < Mt_pad);
    const short* Ag = (const short*)A;
    const short* Bg = (const short*)(is_text ? WTt : WTi);
    const float* bias = is_text ? bt : bi;

    const int wm = w >> 2, wn = w & 3;
    const int scol8 = sg * 8;           // R4: ((l&7)^srow8)*8

    auto stageA = [&](int bI, int h, int kk) {
#pragma unroll
      for (int c = 0; c < 2; ++c) {
        const short* src = Ag + (size_t)(m0 + h * 128 + c * 64 + w * 8 + srow8) * K + kk + scol8;
        load_lds16(src, smem + bI * 32768 + h * 16384 + (c * 4096 + w * 512) * 2);
      }
    };
    auto stageB = [&](int bI, int h, int kk) {
#pragma unroll
      for (int c = 0; c < 2; ++c) {
        const short* src = Bg + (size_t)(n0 + h * 128 + c * 64 + w * 8 + srow8) * K + kk + scol8;
        load_lds16(src, smem + 65536 + bI * 32768 + h * 16384 + (c * 4096 + w * 512) * 2);
      }
    };

    int off2[2];
#pragma unroll
    for (int ks = 0; ks < 2; ++ks)
      off2[ks] = r16 * 64 + (((ks * 4 + (l >> 4)) ^ (l & 7)) * 8);

    unsigned ardA[2][2], ardB[2][2];
#pragma unroll
    for (int bI = 0; bI < 2; ++bI)
#pragma unroll
      for (int ks = 0; ks < 2; ++ks) {
        ardA[bI][ks] = sBase + bI * 32768u + (unsigned)(wm * 16384 + off2[ks] * 2);
        ardB[bI][ks] = sBase + 65536u + bI * 32768u +
                       (unsigned)((wn >> 1) * 16384 + ((wn & 1) * 4096 + off2[ks]) * 2);
      }

    i32x4 a[4][2], b[4][2];
    f32x4 acc[8][4];
    const f32x4 zero = {0.f, 0.f, 0.f, 0.f};
#pragma unroll
    for (int i = 0; i < 8; ++i)
#pragma unroll
      for (int j = 0; j < 4; ++j) acc[i][j] = zero;

    auto mfmaQ = [&](int fmBase, int fnBase) {
#pragma unroll
      for (int fm = 0; fm < 4; ++fm)
#pragma unroll
        for (int fn = 0; fn < 2; ++fn)
#pragma unroll
          for (int ks = 0; ks < 2; ++ks)
            acc[fmBase + fm][fnBase + fn] = __builtin_amdgcn_mfma_f32_16x16x32_bf16(
                asbf(a[fm][ks]), asbf(b[fnBase + fn][ks]),
                acc[fmBase + fm][fnBase + fn], 0, 0, 0);
    };

#define TILE(C) do {                                                          \
    DSRD(a[0][0], ardA[C][0], "0");     DSRD(a[0][1], ardA[C][1], "0");       \
    DSRD(a[1][0], ardA[C][0], "2048");  DSRD(a[1][1], ardA[C][1], "2048");    \
    DSRD(a[2][0], ardA[C][0], "4096");  DSRD(a[2][1], ardA[C][1], "4096");    \
    DSRD(a[3][0], ardA[C][0], "6144");  DSRD(a[3][1], ardA[C][1], "6144");    \
    DSRD(b[0][0], ardB[C][0], "0");     DSRD(b[0][1], ardB[C][1], "0");       \
    DSRD(b[1][0], ardB[C][0], "2048");  DSRD(b[1][1], ardB[C][1], "2048");    \
    stageA(C ^ 1, 0, _kA);                                                    \
    PBAR; LGKM0;                                                              \
    __builtin_amdgcn_s_setprio(1); mfmaQ(0, 0); __builtin_amdgcn_s_setprio(0);\
    SB0; PBAR;                                                                \
    DSRD(b[2][0], ardB[C][0], "4096");  DSRD(b[2][1], ardB[C][1], "4096");    \
    DSRD(b[3][0], ardB[C][0], "6144");  DSRD(b[3][1], ardB[C][1], "6144");    \
    stageA(C ^ 1, 1, _kA);                                                    \
    PBAR; LGKM0;                                                              \
    __builtin_amdgcn_s_setprio(1); mfmaQ(0, 2); __builtin_amdgcn_s_setprio(0);\
    SB0; PBAR;                                                                \
    DSRD(a[0][0], ardA[C][0], "8192");  DSRD(a[0][1], ardA[C][1], "8192");    \
    DSRD(a[1][0], ardA[C][0], "10240"); DSRD(a[1][1], ardA[C][1], "10240");   \
    DSRD(a[2][0], ardA[C][0], "12288"); DSRD(a[2][1], ardA[C][1], "12288");   \
    DSRD(a[3][0], ardA[C][0], "14336"); DSRD(a[3][1], ardA[C][1], "14336");   \
    stageB(C, 0, _kB);                                                        \
    PBAR; LGKM0;                                                              \
    __builtin_amdgcn_s_setprio(1); mfmaQ(4, 2); __builtin_amdgcn_s_setprio(0);\
    SB0; PBAR;                                                                \
    stageB(C, 1, _kB);                                                        \
    asm volatile("s_waitcnt vmcnt(4)" ::: "memory");                          \
    PBAR; SB0;                                                                \
    __builtin_amdgcn_s_setprio(1); mfmaQ(4, 0); __builtin_amdgcn_s_setprio(0);\
    SB0; PBAR;                                                                \
  } while (0)

    stageA(0, 0, 0); stageA(0, 1, 0);
    stageB(0, 0, 0); stageB(0, 1, 0);
    stageB(1, 0, 64); stageB(1, 1, 64);
    asm volatile("s_waitcnt vmcnt(4)" ::: "memory");
    PBAR;

    int _kA, _kB;
    for (int t = 0; t < NT; t += 2) {
      _kA = (t + 1 < NT ? t + 1 : NT - 1) * 64;
      _kB = (t + 2 < NT ? t + 2 : NT - 1) * 64;
      TILE(0);
      _kA = (t + 2 < NT ? t + 2 : NT - 1) * 64;
      _kB = (t + 3 < NT ? t + 3 : NT - 1) * 64;
      TILE(1);
    }
#undef TILE
    asm volatile("s_waitcnt vmcnt(0) lgkmcnt(0)" ::: "memory");

    // epilogue (R4-verified layout)
    float bb[4];
#pragma unroll
    for (int fn = 0; fn < 4; ++fn) bb[fn] = bias[n0 + wn * 64 + fn * 16 + r16];
    if (EPI == 0) {
#pragma unroll
      for (int fm = 0; fm < 8; ++fm) {
        const int grow = m0 + wm * 128 + fm * 16 + r4base;
#pragma unroll
        for (int fn = 0; fn < 4; ++fn) {
          const int gcol = n0 + wn * 64 + fn * 16 + r16;
          f32x4 v = acc[fm][fn];
#pragma unroll
          for (int i = 0; i < 4; ++i)
            Hout[(size_t)(grow + i) * K + gcol] = __float2bfloat16(gelu_exact(v[i] + bb[fn]));
        }
      }
    } else {
#pragma unroll
      for (int fm = 0; fm < 8; ++fm) {
        const int grow = m0 + wm * 128 + fm * 16 + r4base;
        int rid[4];
#pragma unroll
        for (int i = 0; i < 4; ++i) rid[i] = rowid[grow + i];
#pragma unroll
        for (int fn = 0; fn < 4; ++fn) {
          const int gcol = n0 + wn * 64 + fn * 16 + r16;
          f32x4 v = acc[fm][fn];
#pragma unroll
          for (int i = 0; i < 4; ++i) {
            if (rid[i] >= 0) {
              const size_t o = (size_t)rid[i] * K + gcol;
              Out[o] = resid[o] + v[i] + bb[fn];
            }
          }
        }
      }
    }
  } else {
    // ===================== TAIL PATH (R11 verbatim + K-range) =============
    const int tb = bid - 256;           // 0..127
    const int kp = tb & 3;
    const int n0 = ((tb >> 2) & 7) * 256;
    const int m0 = FULLROWS + (tb >> 5) * 128;
    const int kk0 = kp * 512;           // K range [kk0, kk0+512), 16 K-tiles
    const bool is_text = (m0 < Mt_pad);
    const short* Ag = (const short*)A;
    const short* Bg = (const short*)(is_text ? WTt : WTi);

    const int wm = w >> 2, wn = w & 3;
    const int sRowAdj = sg >> 2;
    const int sKAdj = (sg & 3) * 8;

    auto stageA = [&](int bI, int kk) {
      const int mr = w * 8 + srow8;
      const short* src = Ag + (size_t)(m0 + mr * 2 + sRowAdj) * K + kk + sKAdj;
      load_lds16(src, smem + bI * 8192 + w * 1024);
    };
    auto stageB = [&](int bI, int c2, int kk) {
      const int mr = c2 * 64 + w * 8 + srow8;
      const short* src = Bg + (size_t)(n0 + mr * 2 + sRowAdj) * K + kk + sKAdj;
      load_lds16(src, smem + 16384 + bI * 16384 + c2 * 8192 + w * 1024);
    };

    unsigned ardA[2], ardB[2];
#pragma unroll
    for (int bI = 0; bI < 2; ++bI) {
      ardA[bI] = sBase + bI * 8192u + (unsigned)(wm * 4096 + hl * 128 + gr * 16);
      ardB[bI] = sBase + 16384u + bI * 16384u + (unsigned)(wn * 4096 + hl * 128 + gr * 16);
    }

    i32x4 a[4], b[4];
    f32x4 acc[4][4];
    const f32x4 zero = {0.f, 0.f, 0.f, 0.f};
#pragma unroll
    for (int i = 0; i < 4; ++i)
#pragma unroll
      for (int j = 0; j < 4; ++j) acc[i][j] = zero;

#define RD_TILE(C) do {                                                   \
    DSRD(a[0], ardA[C], "0");    DSRD(a[1], ardA[C], "1024");             \
    DSRD(a[2], ardA[C], "2048"); DSRD(a[3], ardA[C], "3072");             \
    DSRD(b[0], ardB[C], "0");    DSRD(b[1], ardB[C], "1024");             \
    DSRD(b[2], ardB[C], "2048"); DSRD(b[3], ardB[C], "3072");             \
  } while (0)

    stageA(0, kk0);
    stageB(0, 0, kk0); stageB(0, 1, kk0);
    VM0;
    PBAR;

    for (int i = 0; i < 16; ++i) {
      const int c = i & 1;
      const int kn = kk0 + (i + 1 < 16 ? i + 1 : 15) * 32;
      stageA(c ^ 1, kn);
      stageB(c ^ 1, 0, kn); stageB(c ^ 1, 1, kn);
      RD_TILE(c);
      LGKM0;
      __builtin_amdgcn_s_setprio(1);
#pragma unroll
      for (int f = 0; f < 4; ++f)
#pragma unroll
        for (int fn = 0; fn < 4; ++fn)
          acc[f][fn] = __builtin_amdgcn_mfma_f32_16x16x32_bf16(
              asbf(a[f]), asbf(b[fn]), acc[f][fn], 0, 0, 0);
      __builtin_amdgcn_s_setprio(0);
      SB0;
      VM0;
      PBAR;
    }
#undef RD_TILE
    asm volatile("s_waitcnt vmcnt(0) lgkmcnt(0)" ::: "memory");

    // raw fp32 partial write: pp[kp][512][2048]
    float* ppk = pp + (size_t)kp * TAILROWS * H_DIM;
    const int mrel = m0 - FULLROWS;
#pragma unroll
    for (int fm = 0; fm < 4; ++fm) {
      const int prow = mrel + wm * 64 + fm * 16 + r4base;
#pragma unroll
      for (int fn = 0; fn < 4; ++fn) {
        const int gcol = n0 + wn * 64 + fn * 16 + r16;
        f32x4 v = acc[fm][fn];
#pragma unroll
        for (int i = 0; i < 4; ++i)
          ppk[(size_t)(prow + i) * H_DIM + gcol] = v[i];
      }
    }
  }
}

// ---------------------------------------------------------------------------
// Combine: sum 4 K-partials for tail rows 8192..8703, apply epilogue.
// 1024 blocks x 256 thr x 4 elems (float4).
// ---------------------------------------------------------------------------
template <int EPI>
__global__ __launch_bounds__(256) void combine_kernel(
    const float* __restrict__ pp, const float* __restrict__ bt,
    const float* __restrict__ bi, const int* __restrict__ ctrl,
    const int* __restrict__ rowid, __hip_bfloat16* __restrict__ Hout,
    const float* __restrict__ resid, float* __restrict__ Out) {
  const int u = blockIdx.x * 256 + threadIdx.x;      // 0..262143
  const int r = u >> 9;                              // 0..511
  const int c = (u & 511) * 4;
  const size_t off = (size_t)r * H_DIM + c;
  float4 s = *(const float4*)(pp + off);
  const float4 s1 = *(const float4*)(pp + (size_t)TAILROWS * H_DIM + off);
  const float4 s2 = *(const float4*)(pp + (size_t)2 * TAILROWS * H_DIM + off);
  const float4 s3 = *(const float4*)(pp + (size_t)3 * TAILROWS * H_DIM + off);
  s.x += s1.x + s2.x + s3.x; s.y += s1.y + s2.y + s3.y;
  s.z += s1.z + s2.z + s3.z; s.w += s1.w + s2.w + s3.w;
  const int grow = FULLROWS + r;
  const float* bias = (grow < ctrl[1]) ? bt : bi;
  const float4 bb = *(const float4*)(bias + c);
  if (EPI == 0) {
    union { ushort u4[4]; ushort4 v4; } pk;
    float z[4] = {s.x + bb.x, s.y + bb.y, s.z + bb.z, s.w + bb.w};
#pragma unroll
    for (int j = 0; j < 4; ++j) {
      __hip_bfloat16 h = __float2bfloat16(0.5f * z[j] * (1.0f + erff(z[j] * 0.70710678118654752f)));
      pk.u4[j] = *(const ushort*)&h;
    }
    *(ushort4*)(Hout + (size_t)grow * H_DIM + c) = pk.v4;
  } else {
    const int rid = rowid[grow];
    if (rid >= 0) {
      const size_t o = (size_t)rid * H_DIM + c;
      const float4 rv = *(const float4*)(resid + o);
      float4 ov;
      ov.x = rv.x + s.x + bb.x; ov.y = rv.y + s.y + bb.y;
      ov.z = rv.z + s.z + bb.z; ov.w = rv.w + s.w + bb.w;
      *(float4*)(Out + o) = ov;
    }
  }
}

// ---------------------------------------------------------------------------
extern "C" void kernel_launch(void* const* d_in, const int* in_sizes, int n_in,
                              void* d_out, int out_size, void* d_ws, size_t ws_size,
                              hipStream_t stream) {
  const float* hidden = (const float*)d_in[0];
  const int*   tt     = (const int*)d_in[1];
  const float* gamma  = (const float*)d_in[2];
  const float* beta   = (const float*)d_in[3];
  const float* tw1    = (const float*)d_in[4];
  const float* tb1    = (const float*)d_in[5];
  const float* tw2    = (const float*)d_in[6];
  const float* tb2    = (const float*)d_in[7];
  const float* iw1    = (const float*)d_in[8];
  const float* ib1    = (const float*)d_in[9];
  const float* iw2    = (const float*)d_in[10];
  const float* ib2    = (const float*)d_in[11];
  float* out = (float*)d_out;

  const int T = in_sizes[1];          // 8192 tokens
  const int K = H_DIM;
  const int maxrows = FULLROWS + TAILROWS;   // 8704

  char* ws = (char*)d_ws;
  int* ctrl  = (int*)(ws);
  int* pos   = (int*)(ws + 4096);
  int* rowid = (int*)(ws + 65536);
  const size_t WOFF = 131072;
  const size_t WSZ = (size_t)K * K * sizeof(__hip_bfloat16);
  __hip_bfloat16* tw1T = (__hip_bfloat16*)(ws + WOFF);
  __hip_bfloat16* tw2T = (__hip_bfloat16*)(ws + WOFF + WSZ);
  __hip_bfloat16* iw1T = (__hip_bfloat16*)(ws + WOFF + 2 * WSZ);
  __hip_bfloat16* iw2T = (__hip_bfloat16*)(ws + WOFF + 3 * WSZ);
  __hip_bfloat16* xg   = (__hip_bfloat16*)(ws + WOFF + 4 * WSZ);
  __hip_bfloat16* hb   = xg + (size_t)maxrows * K;
  float* pp = (float*)(hb + (size_t)maxrows * K);   // 4*512*2048 fp32 = 16.8 MB

  hipMemsetAsync(xg, 0, (size_t)maxrows * K * sizeof(__hip_bfloat16), stream);

  partition_kernel<<<1, 256, 0, stream>>>(tt, T, ctrl, pos, rowid);

  dim3 tg(K / 32, K / 32);
  transpose_to_bf16<<<tg, 256, 0, stream>>>(tw1, tw1T);
  transpose_to_bf16<<<tg, 256, 0, stream>>>(tw2, tw2T);
  transpose_to_bf16<<<tg, 256, 0, stream>>>(iw1, iw1T);
  transpose_to_bf16<<<tg, 256, 0, stream>>>(iw2, iw2T);

  ln_scatter_kernel<<<T, 256, 0, stream>>>(hidden, gamma, beta, pos, xg);

  gemmk<0><<<384, 512, 0, stream>>>(xg, tw1T, iw1T, tb1, ib1, ctrl, rowid,
                                    hb, nullptr, nullptr, pp);
  combine_kernel<0><<<1024, 256, 0, stream>>>(pp, tb1, ib1, ctrl, rowid,
                                              hb, nullptr, nullptr);
  gemmk<1><<<384, 512, 0, stream>>>(hb, tw2T, iw2T, tb2, ib2, ctrl, rowid,
                                    nullptr, hidden, out, pp);
  combine_kernel<1><<<1024, 256, 0, stream>>>(pp, tb2, ib2, ctrl, rowid,
                                              nullptr, hidden, out);
}